// Round 1
// baseline (195.466 us; speedup 1.0000x reference)
//
#include <hip/hip_runtime.h>

// Segment-mean pooling: feats [N, 256] fp32, segment_ids [N] sorted int32,
// out [S, 256] fp32. S = out_size / 256.

#define DCOLS 256
#define D4    64   // DCOLS / 4 float4s per row

// One thread per segment s in [0, S]: starts[s] = lower_bound(ids, s).
// starts[S] naturally = N since all ids < S.
__global__ void seg_starts_kernel(const int* __restrict__ ids, int N, int S,
                                  int* __restrict__ starts) {
    int s = blockIdx.x * blockDim.x + threadIdx.x;
    if (s > S) return;
    int lo = 0, hi = N;
    while (lo < hi) {
        int mid = (lo + hi) >> 1;
        if (ids[mid] < s) lo = mid + 1;
        else hi = mid;
    }
    starts[s] = lo;
}

// One block (256 threads = 4 waves) per segment. Thread t: row-group rg = t>>6,
// column-group cg = t&63 (one float4). Strided accumulation over the segment's
// contiguous rows, LDS reduce across the 4 row-groups, divide, coalesced store.
__global__ __launch_bounds__(256) void seg_mean_kernel(
        const float* __restrict__ feats,
        const int* __restrict__ starts,
        float* __restrict__ out) {
    const int s     = blockIdx.x;
    const int start = starts[s];
    const int end   = starts[s + 1];
    const int count = end - start;

    const int cg = threadIdx.x & 63;
    const int rg = threadIdx.x >> 6;

    const float4* f4 = reinterpret_cast<const float4*>(feats);

    float4 acc = make_float4(0.f, 0.f, 0.f, 0.f);
    for (int r = start + rg; r < end; r += 4) {
        float4 v = f4[(size_t)r * D4 + cg];
        acc.x += v.x; acc.y += v.y; acc.z += v.z; acc.w += v.w;
    }

    __shared__ float4 buf[256];
    buf[threadIdx.x] = acc;
    __syncthreads();

    if (threadIdx.x < 64) {
        float4 a = buf[threadIdx.x];
        float4 b = buf[threadIdx.x + 64];
        float4 c = buf[threadIdx.x + 128];
        float4 d = buf[threadIdx.x + 192];
        float cnt = (float)(count > 0 ? count : 1);
        float4 o;
        o.x = (a.x + b.x + c.x + d.x) / cnt;
        o.y = (a.y + b.y + c.y + d.y) / cnt;
        o.z = (a.z + b.z + c.z + d.z) / cnt;
        o.w = (a.w + b.w + c.w + d.w) / cnt;
        reinterpret_cast<float4*>(out)[(size_t)s * D4 + threadIdx.x] = o;
    }
}

extern "C" void kernel_launch(void* const* d_in, const int* in_sizes, int n_in,
                              void* d_out, int out_size, void* d_ws, size_t ws_size,
                              hipStream_t stream) {
    const float* feats = (const float*)d_in[0];
    const int*   ids   = (const int*)d_in[1];
    // d_in[2] = num_segments scalar on device; derive S from out_size instead.
    const int S = out_size / DCOLS;
    const int N = in_sizes[0] / DCOLS;

    int* starts = (int*)d_ws;  // (S+1) ints

    int t = S + 1;
    seg_starts_kernel<<<(t + 255) / 256, 256, 0, stream>>>(ids, N, S, starts);

    seg_mean_kernel<<<S, 256, 0, stream>>>(feats, starts, (float*)d_out);
}